// Round 1
// 197.053 us; speedup vs baseline: 1.0997x; 1.0997x over previous
//
#include <hip/hip_runtime.h>
#include <hip/hip_bf16.h>
#include <math.h>

#define NB 8
#define NN 4096
#define KK 16
#define MM (NB*NN)
#define CH 32
#define SLOTS 17
#define NCLS 40
#define BIG 3.0e38f
#define CAP 96    // survivors ~25-27 incl. self with 16-bit-bucket threshold (margin unchanged)
#define NBLK2 (MM/8)   // conv2 block count (8 nodes/block)
#define HROW 36        // h1s row stride (f32): 144B -> 16B-aligned, 2-way banks (free)

// Weight table offsets (floats)
#define OW1A 0
#define OB1A 128
#define OW1B 160
#define OB1B 1184
#define OW2A 1216
#define OB2A 2368
#define OW2B 2400
#define OB2B 3424
#define OWC  3456
#define OBC  4736
#define NWTS 4776

typedef short short8 __attribute__((ext_vector_type(8)));
typedef float f32x4  __attribute__((ext_vector_type(4)));

// Module-global scratch (~12 MB): no assumptions about ws_size.
__device__ float4 g_pos4[MM];
__device__ float4 g_nrm4[MM];
__device__ int    g_nbr[MM*KK];
__device__ float  g_u[MM*CH];
__device__ float  g_bmax[NBLK2*CH];   // per-conv2-block channel maxima (no atomics)
__device__ float  g_wts[NWTS];
// Pre-split (bf16 hi/lo) + pre-swizzled B-fragments for 16x16x32 MFMA:
// [ntile][hi/lo][lane][j] with value = W[k=(lane>>4)*8+j][n=ntile*16+(lane&15)]
__device__ __align__(16) unsigned short g_wfrag1[2][2][64][8];
__device__ __align__(16) unsigned short g_wfrag2[2][2][64][8];

__device__ __forceinline__ float bf(const __hip_bfloat16 x) { return __bfloat162float(x); }

__device__ __forceinline__ float ldf(const void* p, int i, bool f32) {
  return f32 ? ((const float*)p)[i] : bf(((const __hip_bfloat16*)p)[i]);
}

__device__ __forceinline__ float angf(float ax, float ay, float az,
                                      float bx, float by, float bz) {
  float cx = ay*bz - az*by;
  float cy = az*bx - ax*bz;
  float cz = ax*by - ay*bx;
  float s  = cx*cx + cy*cy + cz*cz;
  float cn = s > 0.f ? sqrtf(s) : 0.f;
  float d  = ax*bx + ay*by + az*bz;
  return (cn > 0.f || d != 0.f) ? atan2f(cn, d) : 0.f;
}

__device__ __forceinline__ void ppf4(const float4 pi, const float4 ni,
                                     const float4 pj, const float4 nj, float* f) {
  float px = pj.x - pi.x, py = pj.y - pi.y, pz = pj.z - pi.z;
  float s = px*px + py*py + pz*pz;
  f[0] = s > 0.f ? sqrtf(s) : 0.f;
  f[1] = angf(ni.x, ni.y, ni.z, px, py, pz);
  f[2] = angf(nj.x, nj.y, nj.z, px, py, pz);
  f[3] = angf(ni.x, ni.y, ni.z, nj.x, nj.y, nj.z);
}

// monotone f32 -> u32 key (order-preserving for all finite floats)
__device__ __forceinline__ unsigned int fkey(float f) {
  unsigned int u = __float_as_uint(f);
  return (u & 0x80000000u) ? ~u : (u | 0x80000000u);
}
__device__ __forceinline__ float funkey(unsigned int k) {
  unsigned int u = (k & 0x80000000u) ? (k ^ 0x80000000u) : ~k;
  return __uint_as_float(u);
}

// split f32 -> bf16 hi/lo bit patterns
__device__ __forceinline__ void bsplit(float v, unsigned short* hi, unsigned short* lo) {
  __hip_bfloat16 h = __float2bfloat16(v);
  float hf = __bfloat162float(h);
  __hip_bfloat16 l = __float2bfloat16(v - hf);
  *hi = *reinterpret_cast<unsigned short*>(&h);
  *lo = *reinterpret_cast<unsigned short*>(&l);
}

// read 8 f32 from LDS row, split into hi/lo bf16 A-fragments (registers)
__device__ __forceinline__ void afrag(const float* row, short8* ah, short8* al) {
  float4 a = *(const float4*)row;
  float4 b = *(const float4*)(row + 4);
  unsigned short h, l;
  #pragma unroll
  for (int j = 0; j < 4; ++j) {
    bsplit((&a.x)[j], &h, &l); (*ah)[j]   = (short)h; (*al)[j]   = (short)l;
    bsplit((&b.x)[j], &h, &l); (*ah)[j+4] = (short)h; (*al)[j+4] = (short)l;
  }
}

// ---------------- prep: dtype vote (per-block, same verdict) + inputs->float4 +
// ---------------- (block 0 only) weights->fp32 + MFMA B-fragment tables --------------
__global__ __launch_bounds__(256) void prep_kernel(
    const void* __restrict__ pos, const void* __restrict__ nrm,
    const void* w1a, const void* b1a, const void* w1b, const void* b1b,
    const void* w2a, const void* b2a, const void* w2b, const void* b2b,
    const void* wc, const void* bc) {
  __shared__ int sflag;
  const int tid = threadIdx.x;
  const int base = blockIdx.x << 8;
  if (tid < 64) {                                   // wave 0: local dtype vote
    const float* nf = (const float*)nrm;
    const __hip_bfloat16* nh = (const __hip_bfloat16*)nrm;
    int n = base + tid;
    float x = nf[3*n], y = nf[3*n+1], z = nf[3*n+2];
    float ss = x*x + y*y + z*z;
    bool okf = (ss > 0.98f && ss < 1.02f);
    float a = bf(nh[3*n]), b2 = bf(nh[3*n+1]), c2 = bf(nh[3*n+2]);
    float sb = a*a + b2*b2 + c2*c2;
    bool okb = (sb > 0.95f && sb < 1.05f);
    unsigned long long mf = __ballot(okf), mb = __ballot(okb);
    if (tid == 0) sflag = (__popcll(mf) >= __popcll(mb)) ? 1 : 0;
  }
  __syncthreads();
  const bool f32 = sflag != 0;
  {
    int i = base + tid;
    float x = ldf(pos, 3*i, f32), y = ldf(pos, 3*i+1, f32), z = ldf(pos, 3*i+2, f32);
    g_pos4[i] = make_float4(x, y, z, x*x + y*y + z*z);
    float a = ldf(nrm, 3*i, f32), bb = ldf(nrm, 3*i+1, f32), cc = ldf(nrm, 3*i+2, f32);
    g_nrm4[i] = make_float4(a, bb, cc, 0.f);
  }
  if (blockIdx.x == 0) {                            // weight conversion + frag tables
    for (int t = tid; t < 128;  t += 256) g_wts[OW1A + t] = ldf(w1a, t, f32);
    for (int t = tid; t < 32;   t += 256) g_wts[OB1A + t] = ldf(b1a, t, f32);
    for (int t = tid; t < 1024; t += 256) g_wts[OW1B + t] = ldf(w1b, t, f32);
    for (int t = tid; t < 32;   t += 256) g_wts[OB1B + t] = ldf(b1b, t, f32);
    for (int t = tid; t < 1152; t += 256) g_wts[OW2A + t] = ldf(w2a, t, f32);
    for (int t = tid; t < 32;   t += 256) g_wts[OB2A + t] = ldf(b2a, t, f32);
    for (int t = tid; t < 1024; t += 256) g_wts[OW2B + t] = ldf(w2b, t, f32);
    for (int t = tid; t < 32;   t += 256) g_wts[OB2B + t] = ldf(b2b, t, f32);
    for (int t = tid; t < 1280; t += 256) g_wts[OWC  + t] = ldf(wc,  t, f32);
    for (int t = tid; t < 40;   t += 256) g_wts[OBC  + t] = ldf(bc,  t, f32);
    for (int t = tid; t < 4096; t += 256) {
      int which = t >> 11;                 // 0 = w1b, 1 = w2b
      int r = t & 2047;
      int tt = r >> 10;  r &= 1023;
      int hl = r >> 9;   r &= 511;
      int ln = r >> 3;
      int j  = r & 7;
      int k = (ln >> 4)*8 + j;
      int c = tt*16 + (ln & 15);
      float wv = ldf(which ? w2b : w1b, k*CH + c, f32);
      unsigned short hi, lo;
      bsplit(wv, &hi, &lo);
      unsigned short v = hl ? lo : hi;
      if (which) g_wfrag2[tt][hl][ln][j] = v;
      else       g_wfrag1[tt][hl][ln][j] = v;
    }
  }
}

// ---------------- knn + conv1 fused: a block's 64 queries ARE conv1's 64 nodes ----------
// knn phase: SoA xyz tile, interleaved 16-step bisection on 16-bit keys, ballot-based
// survivor push (self-loop included: exact-double rank 0 -> neighbors at ranks 1..16).
// conv1 phase: same-block, no grid sync needed; LDS union overlays the xyz tile with
// conv1's fe/h1s/wsaT/xs; 4 chunks x 16 nodes, per-wave 2 nodes/chunk (MFMA structure
// identical to the validated 256-thread conv1).
__global__ __launch_bounds__(512) void knn_conv1_kernel() {
  __shared__ __align__(16) union SU {
    struct {
      float sx[NN], sy[NN], sz[NN];                 // 49152 B
      unsigned short ilst[64][CAP];                 // 12288 B
      double dlst[8][CAP];                          //  6144 B
    } k;
    struct {
      float fe[272][4];                             //  4352 B (16 nodes * 17 edges)
      float h1s[288*HROW];                          // 41472 B (286 max row read + pad)
      float wsaT[32*HROW];                          //  4608 B (w2a[0:32] as [c][k])
      float xs[16][CH];                             //  2048 B
    } c;
  } u;
  __shared__ unsigned short nbrs[64][KK];           // persists knn -> conv1
  __shared__ unsigned short swcnt[64];              // per-(wave,query) survivor counts

  const int tid  = threadIdx.x;
  const int w    = tid >> 6, lane = tid & 63;
  const int blk  = blockIdx.x;
  const int b    = blk >> 6;                        // 64 blocks per batch
  const int qbw  = ((blk & 63) << 6) | (w << 3);    // first of this wave's 8 queries
  const float4* bp = g_pos4 + b*NN;

  #pragma unroll
  for (int k = 0; k < 8; ++k) {
    int idx = k*512 + tid;
    float4 o = bp[idx];
    u.k.sx[idx] = o.x; u.k.sy[idx] = o.y; u.k.sz[idx] = o.z;
  }
  __syncthreads();

  float q2x[8], q2y[8], q2z[8];
  #pragma unroll
  for (int qq = 0; qq < 8; ++qq) {
    int qi = qbw + qq;
    q2x[qq] = -2.f*u.k.sx[qi]; q2y[qq] = -2.f*u.k.sy[qi]; q2z[qq] = -2.f*u.k.sz[qi];
  }

  float mn[8];
  #pragma unroll
  for (int qq = 0; qq < 8; ++qq) mn[qq] = BIG;
  #pragma unroll 4
  for (int it = 0; it < 64; ++it) {
    int idx = it*64 + lane;
    float ox = u.k.sx[idx], oy = u.k.sy[idx], oz = u.k.sz[idx];
    float ow = __builtin_fmaf(oz, oz, __builtin_fmaf(oy, oy, ox*ox));
    #pragma unroll
    for (int qq = 0; qq < 8; ++qq) {
      float d = __builtin_fmaf(q2x[qq], ox,
                __builtin_fmaf(q2y[qq], oy,
                __builtin_fmaf(q2z[qq], oz, ow)));
      mn[qq] = fminf(mn[qq], d);
    }
  }

  // 16-step bisection over 16-bit truncated keys: threshold bucket is rounded UP
  // (|0xFFFF), so T >= exact 17th lane-min; coarser by <=2^-7 relative -> ~+0.2
  // expected survivors, safe under CAP. Halves the serial SALU chain vs 32-step.
  unsigned int key[8], lo[8], hi[8];
  #pragma unroll
  for (int qq = 0; qq < 8; ++qq) { key[qq] = fkey(mn[qq]) >> 16; lo[qq] = 0u; hi[qq] = 0xFFFFu; }
  #pragma unroll 1
  for (int s = 0; s < 16; ++s) {
    #pragma unroll
    for (int qq = 0; qq < 8; ++qq) {
      unsigned int mid = (lo[qq] + hi[qq]) >> 1;
      int c = (int)__popcll(__ballot(key[qq] <= mid));
      if (c >= 17) hi[qq] = mid; else lo[qq] = mid + 1;
    }
  }
  float Tf[8];
  #pragma unroll
  for (int qq = 0; qq < 8; ++qq) {
    float T = funkey((hi[qq] << 16) | 0xFFFFu);     // >= exact 17th smallest (incl self)
    Tf[qq] = T + 4e-5f + 1e-5f*fabsf(T);            // margin >> f32 d2' abs error
  }

  // filter pass: ballot-ranked push, no atomics, self INCLUDED (d_self ~ 0 <= Tf always)
  unsigned int scnt[8];
  #pragma unroll
  for (int qq = 0; qq < 8; ++qq) scnt[qq] = 0u;
  #pragma unroll 4
  for (int it = 0; it < 64; ++it) {
    int idx = it*64 + lane;
    float ox = u.k.sx[idx], oy = u.k.sy[idx], oz = u.k.sz[idx];
    float ow = __builtin_fmaf(oz, oz, __builtin_fmaf(oy, oy, ox*ox));
    #pragma unroll
    for (int qq = 0; qq < 8; ++qq) {
      float d = __builtin_fmaf(q2x[qq], ox,
                __builtin_fmaf(q2y[qq], oy,
                __builtin_fmaf(q2z[qq], oz, ow)));
      unsigned long long mk = __ballot(d <= Tf[qq]);
      if (mk) {
        unsigned int cbase = scnt[qq];
        if (d <= Tf[qq]) {
          unsigned int r = __builtin_amdgcn_mbcnt_hi(
              (unsigned int)(mk >> 32),
              __builtin_amdgcn_mbcnt_lo((unsigned int)mk, 0u));
          unsigned int p = cbase + r;
          if (p < CAP) u.k.ilst[(w<<3)|qq][p] = (unsigned short)idx;
        }
        scnt[qq] = cbase + (unsigned int)__popcll(mk);
      }
    }
  }
  if (lane == 0) {
    #pragma unroll
    for (int qq = 0; qq < 8; ++qq)
      swcnt[(w<<3)|qq] = (unsigned short)min((int)scnt[qq], CAP);
  }

  // exact double ranking among survivors; self has exact d2 = 0 -> rank 0; neighbors
  // occupy ranks 1..16 -> g_nbr[rank-1]. Also cached in LDS for the conv1 phase.
  #pragma unroll 1
  for (int qq = 0; qq < 8; ++qq) {
    const int qi = qbw + qq;
    const int ql = (w<<3) | qq;
    const int m = (int)swcnt[ql];
    const double mx = (double)u.k.sx[qi], my_ = (double)u.k.sy[qi], mz = (double)u.k.sz[qi];
    const double sqme = (mx*mx + my_*my_) + mz*mz;
    for (int e = lane; e < m; e += 64) {
      int ci = u.k.ilst[ql][e];
      double ox = (double)u.k.sx[ci], oy = (double)u.k.sy[ci], oz = (double)u.k.sz[ci];
      double sqo = (ox*ox + oy*oy) + oz*oz;
      double dt  = (mx*ox + my_*oy) + mz*oz;
      u.k.dlst[w][e] = (sqme + sqo) - 2.0*dt;
    }
    for (int e = lane; e < m; e += 64) {
      double myd = u.k.dlst[w][e];
      int myi = u.k.ilst[ql][e];
      int rank = 0;
      for (int o = 0; o < m; ++o) {                 // broadcast LDS reads
        double od = u.k.dlst[w][o];
        int oi = u.k.ilst[ql][o];
        rank += (od < myd) || (od == myd && oi < myi);
      }
      if (rank >= 1 && rank <= KK) {
        nbrs[ql][rank-1] = (unsigned short)myi;
        g_nbr[(b*NN + qi)*KK + (rank-1)] = b*NN + myi;
      }
    }
  }

  // conv1 constants (global loads; issued while other waves may still rank)
  const int c32 = tid & 31;
  const int quad = lane >> 4, l15 = lane & 15;
  float w1a_c[4];
  #pragma unroll
  for (int f = 0; f < 4; ++f) w1a_c[f] = g_wts[OW1A + f*CH + c32];
  const float b1a_c = g_wts[OB1A + c32];
  short8 bH0 = *(const short8*)&g_wfrag1[0][0][lane][0];
  short8 bL0 = *(const short8*)&g_wfrag1[0][1][lane][0];
  short8 bH1 = *(const short8*)&g_wfrag1[1][0][lane][0];
  short8 bL1 = *(const short8*)&g_wfrag1[1][1][lane][0];
  const float bias0 = g_wts[OB1B + l15];
  const float bias1 = g_wts[OB1B + 16 + l15];

  __syncthreads();                                  // union.k dead past this point

  for (int i2 = tid; i2 < 1024; i2 += 512) {        // stage w2a[0:32] transposed
    int k = i2 >> 5, cc = i2 & 31;
    u.c.wsaT[cc*HROW + k] = g_wts[OW2A + i2];
  }
  const int nbb = b*NN + ((blk & 63) << 6);         // global node base of this block

  #pragma unroll 1
  for (int ck = 0; ck < 4; ++ck) {                  // 4 chunks x 16 nodes
    const int nloc0 = ck << 4;
    if (tid < 272) {
      int ns = tid / 17, slot = tid - ns*17;
      int iloc = nloc0 + ns;
      int ig = nbb + iloc;
      int jg = (slot < KK) ? (b*NN + (int)nbrs[iloc][slot]) : ig;  // slot 16 = self
      ppf4(g_pos4[ig], g_nrm4[ig], g_pos4[jg], g_nrm4[jg], u.c.fe[tid]);
    }
    __syncthreads();
    #pragma unroll
    for (int it = 0; it < 17; ++it) {               // h-phase: f32, single store
      int idx = it*512 + tid;
      int e = idx >> 5;                             // c == tid&31; row == e (0..271)
      float4 f4 = *(const float4*)u.c.fe[e];
      float h = b1a_c + f4.x*w1a_c[0] + f4.y*w1a_c[1] + f4.z*w1a_c[2] + f4.w*w1a_c[3];
      u.c.h1s[e*HROW + c32] = fmaxf(h, 0.f);
    }
    __syncthreads();
    #pragma unroll
    for (int ni = 0; ni < 2; ++ni) {                // MFMA phase: 2 nodes/wave
      const int n16 = w*2 + ni;                     // 0..15
      const int rbase = n16*17;
      short8 ah0, al0, ah1, al1;
      afrag(&u.c.h1s[(rbase      + l15)*HROW + quad*8], &ah0, &al0);
      afrag(&u.c.h1s[(rbase + 16 + l15)*HROW + quad*8], &ah1, &al1);
      f32x4 a00 = {0.f,0.f,0.f,0.f}, a01 = a00, a10 = a00, a11 = a00;
      a00 = __builtin_amdgcn_mfma_f32_16x16x32_bf16(ah0, bH0, a00, 0, 0, 0);
      a00 = __builtin_amdgcn_mfma_f32_16x16x32_bf16(ah0, bL0, a00, 0, 0, 0);
      a00 = __builtin_amdgcn_mfma_f32_16x16x32_bf16(al0, bH0, a00, 0, 0, 0);
      a01 = __builtin_amdgcn_mfma_f32_16x16x32_bf16(ah0, bH1, a01, 0, 0, 0);
      a01 = __builtin_amdgcn_mfma_f32_16x16x32_bf16(ah0, bL1, a01, 0, 0, 0);
      a01 = __builtin_amdgcn_mfma_f32_16x16x32_bf16(al0, bH1, a01, 0, 0, 0);
      a10 = __builtin_amdgcn_mfma_f32_16x16x32_bf16(ah1, bH0, a10, 0, 0, 0);
      a10 = __builtin_amdgcn_mfma_f32_16x16x32_bf16(ah1, bL0, a10, 0, 0, 0);
      a10 = __builtin_amdgcn_mfma_f32_16x16x32_bf16(al1, bH0, a10, 0, 0, 0);
      a11 = __builtin_amdgcn_mfma_f32_16x16x32_bf16(ah1, bH1, a11, 0, 0, 0);
      a11 = __builtin_amdgcn_mfma_f32_16x16x32_bf16(ah1, bL1, a11, 0, 0, 0);
      a11 = __builtin_amdgcn_mfma_f32_16x16x32_bf16(al1, bH1, a11, 0, 0, 0);
      float m0 = fmaxf(fmaxf(a00[0], a00[1]), fmaxf(a00[2], a00[3]));
      float m1 = fmaxf(fmaxf(a01[0], a01[1]), fmaxf(a01[2], a01[3]));
      if (quad == 0) { m0 = fmaxf(m0, a10[0]); m1 = fmaxf(m1, a11[0]); }
      m0 = fmaxf(m0, __shfl_xor(m0, 16)); m0 = fmaxf(m0, __shfl_xor(m0, 32));
      m1 = fmaxf(m1, __shfl_xor(m1, 16)); m1 = fmaxf(m1, __shfl_xor(m1, 32));
      if (quad == 0) {
        u.c.xs[n16][l15]      = fmaxf(m0 + bias0, 0.f);  // x1 = relu(max + b1b)
        u.c.xs[n16][16 + l15] = fmaxf(m1 + bias1, 0.f);
      }
    }
    __syncthreads();
    {
      int ns = tid >> 5;                            // 0..15
      float uu = 0.f;
      #pragma unroll
      for (int k4 = 0; k4 < 8; ++k4) {
        float4 x4 = *(const float4*)&u.c.xs[ns][4*k4];
        float4 w4 = *(const float4*)&u.c.wsaT[c32*HROW + 4*k4];
        uu += x4.x*w4.x + x4.y*w4.y + x4.z*w4.z + x4.w*w4.w;
      }
      g_u[(nbb + nloc0 + ns)*CH + c32] = uu;        // u = x1 @ w2a[0:32,:]
    }
    __syncthreads();
  }
}

// ---------------- conv2: f32 LDS h + register-split MFMA + block-max -> g_bmax ----------
__global__ __launch_bounds__(256) void conv2_kernel() {
  __shared__ __align__(16) float fe[136][4];
  __shared__ int jn[136];
  __shared__ __align__(16) float h1s[152*HROW];
  __shared__ float xs[8][CH];
  const int tid = threadIdx.x;
  const int c = tid & 31;
  const int lane = tid & 63, wv = tid >> 6;
  const int quad = lane >> 4, l15 = lane & 15;
  const int node0 = blockIdx.x << 3;
  float w2aL_c[4];
  #pragma unroll
  for (int f = 0; f < 4; ++f) w2aL_c[f] = g_wts[OW2A + (CH + f)*CH + c];
  const float b2a_c = g_wts[OB2A + c];
  short8 bH0 = *(const short8*)&g_wfrag2[0][0][lane][0];
  short8 bL0 = *(const short8*)&g_wfrag2[0][1][lane][0];
  short8 bH1 = *(const short8*)&g_wfrag2[1][0][lane][0];
  short8 bL1 = *(const short8*)&g_wfrag2[1][1][lane][0];
  const float bias0 = g_wts[OB2B + l15];
  const float bias1 = g_wts[OB2B + 16 + l15];

  if (tid < 136) {
    int ns = tid / 17, slot = tid - ns*17;
    int i = node0 + ns;
    int j = (slot < KK) ? g_nbr[i*KK + slot] : i;
    jn[tid] = j;
    ppf4(g_pos4[i], g_nrm4[i], g_pos4[j], g_nrm4[j], fe[tid]);
  }
  __syncthreads();
  #pragma unroll
  for (int it = 0; it < 17; ++it) {
    int idx = it*256 + tid;
    int e = idx >> 5;
    float4 f4 = *(const float4*)fe[e];
    float uv = g_u[jn[e]*CH + c];             // x_j @ w2a[0:32] precomputed
    float h = b2a_c + uv + f4.x*w2aL_c[0] + f4.y*w2aL_c[1] + f4.z*w2aL_c[2] + f4.w*w2aL_c[3];
    h1s[e*HROW + c] = fmaxf(h, 0.f);
  }
  __syncthreads();
  #pragma unroll
  for (int ni = 0; ni < 2; ++ni) {
    const int n8 = wv*2 + ni;
    const int rbase = n8*17;
    short8 ah0, al0, ah1, al1;
    afrag(&h1s[(rbase      + l15)*HROW + quad*8], &ah0, &al0);
    afrag(&h1s[(rbase + 16 + l15)*HROW + quad*8], &ah1, &al1);
    f32x4 a00 = {0.f,0.f,0.f,0.f}, a01 = a00, a10 = a00, a11 = a00;
    a00 = __builtin_amdgcn_mfma_f32_16x16x32_bf16(ah0, bH0, a00, 0, 0, 0);
    a00 = __builtin_amdgcn_mfma_f32_16x16x32_bf16(ah0, bL0, a00, 0, 0, 0);
    a00 = __builtin_amdgcn_mfma_f32_16x16x32_bf16(al0, bH0, a00, 0, 0, 0);
    a01 = __builtin_amdgcn_mfma_f32_16x16x32_bf16(ah0, bH1, a01, 0, 0, 0);
    a01 = __builtin_amdgcn_mfma_f32_16x16x32_bf16(ah0, bL1, a01, 0, 0, 0);
    a01 = __builtin_amdgcn_mfma_f32_16x16x32_bf16(al0, bH1, a01, 0, 0, 0);
    a10 = __builtin_amdgcn_mfma_f32_16x16x32_bf16(ah1, bH0, a10, 0, 0, 0);
    a10 = __builtin_amdgcn_mfma_f32_16x16x32_bf16(ah1, bL0, a10, 0, 0, 0);
    a10 = __builtin_amdgcn_mfma_f32_16x16x32_bf16(al1, bH0, a10, 0, 0, 0);
    a11 = __builtin_amdgcn_mfma_f32_16x16x32_bf16(ah1, bH1, a11, 0, 0, 0);
    a11 = __builtin_amdgcn_mfma_f32_16x16x32_bf16(ah1, bL1, a11, 0, 0, 0);
    a11 = __builtin_amdgcn_mfma_f32_16x16x32_bf16(al1, bH1, a11, 0, 0, 0);
    float m0 = fmaxf(fmaxf(a00[0], a00[1]), fmaxf(a00[2], a00[3]));
    float m1 = fmaxf(fmaxf(a01[0], a01[1]), fmaxf(a01[2], a01[3]));
    if (quad == 0) { m0 = fmaxf(m0, a10[0]); m1 = fmaxf(m1, a11[0]); }
    m0 = fmaxf(m0, __shfl_xor(m0, 16)); m0 = fmaxf(m0, __shfl_xor(m0, 32));
    m1 = fmaxf(m1, __shfl_xor(m1, 16)); m1 = fmaxf(m1, __shfl_xor(m1, 32));
    if (quad == 0) {
      xs[n8][l15]      = fmaxf(m0 + bias0, 0.f);    // x2 = relu(max + b2b)
      xs[n8][16 + l15] = fmaxf(m1 + bias1, 0.f);
    }
  }
  __syncthreads();
  if (tid < CH) {                             // block max -> plain coalesced store
    float m2 = xs[0][c];
    #pragma unroll
    for (int r = 1; r < 8; ++r) m2 = fmaxf(m2, xs[r][c]);
    g_bmax[blockIdx.x*CH + c] = m2;
  }
}

// ---------------- head: two-stage max over g_bmax + 32->40 matmul (f32 out) -------------
__global__ __launch_bounds__(256) void head_kernel(float* __restrict__ out) {
  __shared__ float red[8][CH];
  __shared__ float gm[CH];
  const int g = blockIdx.x;
  const int c = threadIdx.x & 31, sub = threadIdx.x >> 5;
  const float* base = g_bmax + (size_t)(g*512 + sub*64)*CH;   // 512 conv2 blocks/graph
  float mx = 0.f;                                             // x2 >= 0 (relu)
  #pragma unroll
  for (int n = 0; n < 64; ++n) mx = fmaxf(mx, base[n*CH + c]);
  red[sub][c] = mx;
  __syncthreads();
  if (threadIdx.x < CH) {
    float m2 = red[0][c];
    #pragma unroll
    for (int r = 1; r < 8; ++r) m2 = fmaxf(m2, red[r][c]);
    gm[c] = m2;
  }
  __syncthreads();
  if (threadIdx.x < NCLS) {
    int co = threadIdx.x;
    float s = g_wts[OBC + co];
    #pragma unroll
    for (int f = 0; f < CH; ++f) s += gm[f] * g_wts[OWC + f*NCLS + co];
    out[g*NCLS + co] = s;                     // float32 out (reference dtype)
  }
}

extern "C" void kernel_launch(void* const* d_in, const int* in_sizes, int n_in,
                              void* d_out, int out_size, void* d_ws, size_t ws_size,
                              hipStream_t stream) {
  const void* pos = d_in[0];
  const void* nrm = d_in[1];
  // d_in[2] = batch (int32) -- unused, batches are uniform
  const void* w1a = d_in[3];
  const void* b1a = d_in[4];
  const void* w1b = d_in[5];
  const void* b1b = d_in[6];
  const void* w2a = d_in[7];
  const void* b2a = d_in[8];
  const void* w2b = d_in[9];
  const void* b2b = d_in[10];
  const void* wc  = d_in[11];
  const void* bc  = d_in[12];

  prep_kernel<<<MM/256, 256, 0, stream>>>(pos, nrm, w1a, b1a, w1b, b1b,
                                          w2a, b2a, w2b, b2b, wc, bc);
  knn_conv1_kernel<<<MM/64, 512, 0, stream>>>();
  conv2_kernel<<<MM/8, 256, 0, stream>>>();
  head_kernel<<<NB, 256, 0, stream>>>((float*)d_out);
}

// Round 2
// 191.720 us; speedup vs baseline: 1.1303x; 1.0278x over previous
//
#include <hip/hip_runtime.h>
#include <hip/hip_bf16.h>
#include <math.h>

#define NB 8
#define NN 4096
#define KK 16
#define MM (NB*NN)
#define CH 32
#define SLOTS 17
#define NCLS 40
#define BIG 3.0e38f
#define CAP 96    // survivors ~25-27 incl. self with 16-bit-bucket threshold (margin unchanged)
#define NBLK2 (MM/64)  // conv2 block count (64 nodes/block)
#define HROW 36        // h1s row stride (f32): 144B -> 16B-aligned, 2-way banks (free)

// Weight table offsets (floats)
#define OW1A 0
#define OB1A 128
#define OW1B 160
#define OB1B 1184
#define OW2A 1216
#define OB2A 2368
#define OW2B 2400
#define OB2B 3424
#define OWC  3456
#define OBC  4736
#define NWTS 4776

typedef short short8 __attribute__((ext_vector_type(8)));
typedef float f32x4  __attribute__((ext_vector_type(4)));
typedef float f32x2  __attribute__((ext_vector_type(2)));

// Module-global scratch (~21 MB): no assumptions about ws_size.
__device__ float4 g_pos4[MM];
__device__ float4 g_nrm4[MM];
__device__ int    g_nbr[MM*KK];
__device__ float  g_u[MM*CH];
__device__ float  g_bmax[NBLK2*CH];   // per-conv2-block channel maxima (no atomics)
__device__ float  g_wts[NWTS];
__device__ __align__(16) float4 g_fe4[MM*SLOTS];   // PPF features cached conv1 -> conv2
// Pre-split (bf16 hi/lo) + pre-swizzled B-fragments for 16x16x32 MFMA:
// [ntile][hi/lo][lane][j] with value = W[k=(lane>>4)*8+j][n=ntile*16+(lane&15)]
__device__ __align__(16) unsigned short g_wfrag1[2][2][64][8];
__device__ __align__(16) unsigned short g_wfrag2[2][2][64][8];

__device__ __forceinline__ float bf(const __hip_bfloat16 x) { return __bfloat162float(x); }

__device__ __forceinline__ float ldf(const void* p, int i, bool f32) {
  return f32 ? ((const float*)p)[i] : bf(((const __hip_bfloat16*)p)[i]);
}

__device__ __forceinline__ float angf(float ax, float ay, float az,
                                      float bx, float by, float bz) {
  float cx = ay*bz - az*by;
  float cy = az*bx - ax*bz;
  float cz = ax*by - ay*bx;
  float s  = cx*cx + cy*cy + cz*cz;
  float cn = s > 0.f ? sqrtf(s) : 0.f;
  float d  = ax*bx + ay*by + az*bz;
  return (cn > 0.f || d != 0.f) ? atan2f(cn, d) : 0.f;
}

__device__ __forceinline__ void ppf4(const float4 pi, const float4 ni,
                                     const float4 pj, const float4 nj, float* f) {
  float px = pj.x - pi.x, py = pj.y - pi.y, pz = pj.z - pi.z;
  float s = px*px + py*py + pz*pz;
  f[0] = s > 0.f ? sqrtf(s) : 0.f;
  f[1] = angf(ni.x, ni.y, ni.z, px, py, pz);
  f[2] = angf(nj.x, nj.y, nj.z, px, py, pz);
  f[3] = angf(ni.x, ni.y, ni.z, nj.x, nj.y, nj.z);
}

// monotone f32 -> u32 key (order-preserving for all finite floats)
__device__ __forceinline__ unsigned int fkey(float f) {
  unsigned int u = __float_as_uint(f);
  return (u & 0x80000000u) ? ~u : (u | 0x80000000u);
}
__device__ __forceinline__ float funkey(unsigned int k) {
  unsigned int u = (k & 0x80000000u) ? (k ^ 0x80000000u) : ~k;
  return __uint_as_float(u);
}

__device__ __forceinline__ unsigned int mbcnt64(unsigned long long m) {
  return __builtin_amdgcn_mbcnt_hi((unsigned int)(m >> 32),
         __builtin_amdgcn_mbcnt_lo((unsigned int)m, 0u));
}

// split f32 -> bf16 hi/lo bit patterns
__device__ __forceinline__ void bsplit(float v, unsigned short* hi, unsigned short* lo) {
  __hip_bfloat16 h = __float2bfloat16(v);
  float hf = __bfloat162float(h);
  __hip_bfloat16 l = __float2bfloat16(v - hf);
  *hi = *reinterpret_cast<unsigned short*>(&h);
  *lo = *reinterpret_cast<unsigned short*>(&l);
}

// read 8 f32 from LDS row, split into hi/lo bf16 A-fragments (registers)
__device__ __forceinline__ void afrag(const float* row, short8* ah, short8* al) {
  float4 a = *(const float4*)row;
  float4 b = *(const float4*)(row + 4);
  unsigned short h, l;
  #pragma unroll
  for (int j = 0; j < 4; ++j) {
    bsplit((&a.x)[j], &h, &l); (*ah)[j]   = (short)h; (*al)[j]   = (short)l;
    bsplit((&b.x)[j], &h, &l); (*ah)[j+4] = (short)h; (*al)[j+4] = (short)l;
  }
}

// ---------------- prep: dtype vote (per-block, same verdict) + inputs->float4 +
// ---------------- (block 0 only) weights->fp32 + MFMA B-fragment tables --------------
__global__ __launch_bounds__(256) void prep_kernel(
    const void* __restrict__ pos, const void* __restrict__ nrm,
    const void* w1a, const void* b1a, const void* w1b, const void* b1b,
    const void* w2a, const void* b2a, const void* w2b, const void* b2b,
    const void* wc, const void* bc) {
  __shared__ int sflag;
  const int tid = threadIdx.x;
  const int base = blockIdx.x << 8;
  if (tid < 64) {                                   // wave 0: local dtype vote
    const float* nf = (const float*)nrm;
    const __hip_bfloat16* nh = (const __hip_bfloat16*)nrm;
    int n = base + tid;
    float x = nf[3*n], y = nf[3*n+1], z = nf[3*n+2];
    float ss = x*x + y*y + z*z;
    bool okf = (ss > 0.98f && ss < 1.02f);
    float a = bf(nh[3*n]), b2 = bf(nh[3*n+1]), c2 = bf(nh[3*n+2]);
    float sb = a*a + b2*b2 + c2*c2;
    bool okb = (sb > 0.95f && sb < 1.05f);
    unsigned long long mf = __ballot(okf), mb = __ballot(okb);
    if (tid == 0) sflag = (__popcll(mf) >= __popcll(mb)) ? 1 : 0;
  }
  __syncthreads();
  const bool f32 = sflag != 0;
  {
    int i = base + tid;
    float x = ldf(pos, 3*i, f32), y = ldf(pos, 3*i+1, f32), z = ldf(pos, 3*i+2, f32);
    g_pos4[i] = make_float4(x, y, z, x*x + y*y + z*z);
    float a = ldf(nrm, 3*i, f32), bb = ldf(nrm, 3*i+1, f32), cc = ldf(nrm, 3*i+2, f32);
    g_nrm4[i] = make_float4(a, bb, cc, 0.f);
  }
  if (blockIdx.x == 0) {                            // weight conversion + frag tables
    for (int t = tid; t < 128;  t += 256) g_wts[OW1A + t] = ldf(w1a, t, f32);
    for (int t = tid; t < 32;   t += 256) g_wts[OB1A + t] = ldf(b1a, t, f32);
    for (int t = tid; t < 1024; t += 256) g_wts[OW1B + t] = ldf(w1b, t, f32);
    for (int t = tid; t < 32;   t += 256) g_wts[OB1B + t] = ldf(b1b, t, f32);
    for (int t = tid; t < 1152; t += 256) g_wts[OW2A + t] = ldf(w2a, t, f32);
    for (int t = tid; t < 32;   t += 256) g_wts[OB2A + t] = ldf(b2a, t, f32);
    for (int t = tid; t < 1024; t += 256) g_wts[OW2B + t] = ldf(w2b, t, f32);
    for (int t = tid; t < 32;   t += 256) g_wts[OB2B + t] = ldf(b2b, t, f32);
    for (int t = tid; t < 1280; t += 256) g_wts[OWC  + t] = ldf(wc,  t, f32);
    for (int t = tid; t < 40;   t += 256) g_wts[OBC  + t] = ldf(bc,  t, f32);
    for (int t = tid; t < 4096; t += 256) {
      int which = t >> 11;                 // 0 = w1b, 1 = w2b
      int r = t & 2047;
      int tt = r >> 10;  r &= 1023;
      int hl = r >> 9;   r &= 511;
      int ln = r >> 3;
      int j  = r & 7;
      int k = (ln >> 4)*8 + j;
      int c = tt*16 + (ln & 15);
      float wv = ldf(which ? w2b : w1b, k*CH + c, f32);
      unsigned short hi, lo;
      bsplit(wv, &hi, &lo);
      unsigned short v = hl ? lo : hi;
      if (which) g_wfrag2[tt][hl][ln][j] = v;
      else       g_wfrag1[tt][hl][ln][j] = v;
    }
  }
}

// ---------------- knn + conv1 fused: a block's 64 queries ARE conv1's 64 nodes ----------
// knn: SoA xyz tile; PACKED candidate pairs (v_pk_fma_f32 + v_min3_f32) in both distance
// passes; 16-step bisection on 16-bit keys; ballot-ranked survivor push (no atomics,
// self-loop included -> exact-double rank 0, neighbors at ranks 1..16).
// conv1: same-block (no grid sync), LDS union overlays xyz tile; 4 chunks x 16 nodes;
// ALSO caches ppf features to g_fe4 for conv2 (identical values, computed once).
__global__ __launch_bounds__(512) void knn_conv1_kernel() {
  __shared__ __align__(16) union SU {
    struct {
      float sx[NN], sy[NN], sz[NN];                 // 49152 B
      unsigned short ilst[64][CAP];                 // 12288 B
      double dlst[8][CAP];                          //  6144 B
    } k;
    struct {
      float fe[272][4];                             //  4352 B (16 nodes * 17 edges)
      float h1s[288*HROW];                          // 41472 B (286 max row read + pad)
      float wsaT[32*HROW];                          //  4608 B (w2a[0:32] as [c][k])
      float xs[16][CH];                             //  2048 B
    } c;
  } u;
  __shared__ unsigned short nbrs[64][KK];           // persists knn -> conv1
  __shared__ unsigned short swcnt[64];              // per-(wave,query) survivor counts

  const int tid  = threadIdx.x;
  const int w    = tid >> 6, lane = tid & 63;
  const int blk  = blockIdx.x;
  const int b    = blk >> 6;                        // 64 blocks per batch
  const int qbw  = ((blk & 63) << 6) | (w << 3);    // first of this wave's 8 queries
  const float4* bp = g_pos4 + b*NN;

  #pragma unroll
  for (int k = 0; k < 8; ++k) {
    int idx = k*512 + tid;
    float4 o = bp[idx];
    u.k.sx[idx] = o.x; u.k.sy[idx] = o.y; u.k.sz[idx] = o.z;
  }
  __syncthreads();

  float q2x[8], q2y[8], q2z[8];
  #pragma unroll
  for (int qq = 0; qq < 8; ++qq) {
    int qi = qbw + qq;
    q2x[qq] = -2.f*u.k.sx[qi]; q2y[qq] = -2.f*u.k.sy[qi]; q2z[qq] = -2.f*u.k.sz[qi];
  }
  const f32x2* sx2 = (const f32x2*)u.k.sx;
  const f32x2* sy2 = (const f32x2*)u.k.sy;
  const f32x2* sz2 = (const f32x2*)u.k.sz;

  // min pass: packed candidate pairs. d' = |o|^2 - 2 q.o  (shifted squared distance)
  float mn[8];
  #pragma unroll
  for (int qq = 0; qq < 8; ++qq) mn[qq] = BIG;
  #pragma unroll 4
  for (int it = 0; it < 32; ++it) {
    int p = it*64 + lane;                           // candidate pair index
    f32x2 ox = sx2[p], oy = sy2[p], oz = sz2[p];
    f32x2 ow = __builtin_elementwise_fma(oz, oz,
               __builtin_elementwise_fma(oy, oy, ox*ox));
    #pragma unroll
    for (int qq = 0; qq < 8; ++qq) {
      f32x2 qx = {q2x[qq], q2x[qq]};
      f32x2 qy = {q2y[qq], q2y[qq]};
      f32x2 qz = {q2z[qq], q2z[qq]};
      f32x2 d = __builtin_elementwise_fma(qx, ox,
                __builtin_elementwise_fma(qy, oy,
                __builtin_elementwise_fma(qz, oz, ow)));
      mn[qq] = fminf(fminf(d[0], d[1]), mn[qq]);    // -> v_min3_f32
    }
  }

  // 16-step bisection over 16-bit truncated keys: threshold bucket is rounded UP
  // (|0xFFFF), so T >= exact 17th lane-min; coarser by <=2^-7 relative -> ~+0.2
  // expected survivors, safe under CAP.
  unsigned int key[8], lo[8], hi[8];
  #pragma unroll
  for (int qq = 0; qq < 8; ++qq) { key[qq] = fkey(mn[qq]) >> 16; lo[qq] = 0u; hi[qq] = 0xFFFFu; }
  #pragma unroll 1
  for (int s = 0; s < 16; ++s) {
    #pragma unroll
    for (int qq = 0; qq < 8; ++qq) {
      unsigned int mid = (lo[qq] + hi[qq]) >> 1;
      int c = (int)__popcll(__ballot(key[qq] <= mid));
      if (c >= 17) hi[qq] = mid; else lo[qq] = mid + 1;
    }
  }
  float Tf[8];
  #pragma unroll
  for (int qq = 0; qq < 8; ++qq) {
    float T = funkey((hi[qq] << 16) | 0xFFFFu);     // >= exact 17th smallest (incl self)
    Tf[qq] = T + 4e-5f + 1e-5f*fabsf(T);            // margin >> f32 d2' abs error
  }

  // filter pass: packed pairs, ballot-ranked push, no atomics, self INCLUDED
  unsigned int scnt[8];
  #pragma unroll
  for (int qq = 0; qq < 8; ++qq) scnt[qq] = 0u;
  #pragma unroll 2
  for (int it = 0; it < 32; ++it) {
    int p = it*64 + lane;
    f32x2 ox = sx2[p], oy = sy2[p], oz = sz2[p];
    f32x2 ow = __builtin_elementwise_fma(oz, oz,
               __builtin_elementwise_fma(oy, oy, ox*ox));
    #pragma unroll
    for (int qq = 0; qq < 8; ++qq) {
      f32x2 qx = {q2x[qq], q2x[qq]};
      f32x2 qy = {q2y[qq], q2y[qq]};
      f32x2 qz = {q2z[qq], q2z[qq]};
      f32x2 d = __builtin_elementwise_fma(qx, ox,
                __builtin_elementwise_fma(qy, oy,
                __builtin_elementwise_fma(qz, oz, ow)));
      bool h0 = d[0] <= Tf[qq];
      bool h1 = d[1] <= Tf[qq];
      unsigned long long mk0 = __ballot(h0);
      unsigned long long mk1 = __ballot(h1);
      if (mk0 | mk1) {
        unsigned int cbase = scnt[qq];
        if (h0) {
          unsigned int pos = cbase + mbcnt64(mk0);
          if (pos < CAP) u.k.ilst[(w<<3)|qq][pos] = (unsigned short)(2*p);
        }
        cbase += (unsigned int)__popcll(mk0);
        if (h1) {
          unsigned int pos = cbase + mbcnt64(mk1);
          if (pos < CAP) u.k.ilst[(w<<3)|qq][pos] = (unsigned short)(2*p + 1);
        }
        scnt[qq] = cbase + (unsigned int)__popcll(mk1);
      }
    }
  }
  if (lane == 0) {
    #pragma unroll
    for (int qq = 0; qq < 8; ++qq)
      swcnt[(w<<3)|qq] = (unsigned short)min((int)scnt[qq], CAP);
  }

  // exact double ranking among survivors; self has exact d2 = 0 -> rank 0; neighbors
  // occupy ranks 1..16 -> g_nbr[rank-1]. Also cached in LDS for the conv1 phase.
  #pragma unroll 1
  for (int qq = 0; qq < 8; ++qq) {
    const int qi = qbw + qq;
    const int ql = (w<<3) | qq;
    const int m = (int)swcnt[ql];
    const double mx = (double)u.k.sx[qi], my_ = (double)u.k.sy[qi], mz = (double)u.k.sz[qi];
    const double sqme = (mx*mx + my_*my_) + mz*mz;
    for (int e = lane; e < m; e += 64) {
      int ci = u.k.ilst[ql][e];
      double ox = (double)u.k.sx[ci], oy = (double)u.k.sy[ci], oz = (double)u.k.sz[ci];
      double sqo = (ox*ox + oy*oy) + oz*oz;
      double dt  = (mx*ox + my_*oy) + mz*oz;
      u.k.dlst[w][e] = (sqme + sqo) - 2.0*dt;
    }
    for (int e = lane; e < m; e += 64) {
      double myd = u.k.dlst[w][e];
      int myi = u.k.ilst[ql][e];
      int rank = 0;
      for (int o = 0; o < m; ++o) {                 // broadcast LDS reads
        double od = u.k.dlst[w][o];
        int oi = u.k.ilst[ql][o];
        rank += (od < myd) || (od == myd && oi < myi);
      }
      if (rank >= 1 && rank <= KK) {
        nbrs[ql][rank-1] = (unsigned short)myi;
        g_nbr[(b*NN + qi)*KK + (rank-1)] = b*NN + myi;
      }
    }
  }

  // conv1 constants (global loads; issued while other waves may still rank)
  const int c32 = tid & 31;
  const int quad = lane >> 4, l15 = lane & 15;
  float w1a_c[4];
  #pragma unroll
  for (int f = 0; f < 4; ++f) w1a_c[f] = g_wts[OW1A + f*CH + c32];
  const float b1a_c = g_wts[OB1A + c32];
  short8 bH0 = *(const short8*)&g_wfrag1[0][0][lane][0];
  short8 bL0 = *(const short8*)&g_wfrag1[0][1][lane][0];
  short8 bH1 = *(const short8*)&g_wfrag1[1][0][lane][0];
  short8 bL1 = *(const short8*)&g_wfrag1[1][1][lane][0];
  const float bias0 = g_wts[OB1B + l15];
  const float bias1 = g_wts[OB1B + 16 + l15];

  __syncthreads();                                  // union.k dead past this point

  for (int i2 = tid; i2 < 1024; i2 += 512) {        // stage w2a[0:32] transposed
    int k = i2 >> 5, cc = i2 & 31;
    u.c.wsaT[cc*HROW + k] = g_wts[OW2A + i2];
  }
  const int nbb = b*NN + ((blk & 63) << 6);         // global node base of this block

  #pragma unroll 1
  for (int ck = 0; ck < 4; ++ck) {                  // 4 chunks x 16 nodes
    const int nloc0 = ck << 4;
    if (tid < 272) {
      int ns = tid / 17, slot = tid - ns*17;
      int iloc = nloc0 + ns;
      int ig = nbb + iloc;
      int jg = (slot < KK) ? (b*NN + (int)nbrs[iloc][slot]) : ig;  // slot 16 = self
      float f[4];
      ppf4(g_pos4[ig], g_nrm4[ig], g_pos4[jg], g_nrm4[jg], f);
      float4 fv = make_float4(f[0], f[1], f[2], f[3]);
      *(float4*)u.c.fe[tid] = fv;
      g_fe4[(size_t)(nbb + nloc0)*SLOTS + tid] = fv;  // cache for conv2 (bit-identical)
    }
    __syncthreads();
    #pragma unroll
    for (int it = 0; it < 17; ++it) {               // h-phase: f32, single store
      int idx = it*512 + tid;
      int e = idx >> 5;                             // c == tid&31; row == e (0..271)
      float4 f4 = *(const float4*)u.c.fe[e];
      float h = b1a_c + f4.x*w1a_c[0] + f4.y*w1a_c[1] + f4.z*w1a_c[2] + f4.w*w1a_c[3];
      u.c.h1s[e*HROW + c32] = fmaxf(h, 0.f);
    }
    __syncthreads();
    #pragma unroll
    for (int ni = 0; ni < 2; ++ni) {                // MFMA phase: 2 nodes/wave
      const int n16 = w*2 + ni;                     // 0..15
      const int rbase = n16*17;
      short8 ah0, al0, ah1, al1;
      afrag(&u.c.h1s[(rbase      + l15)*HROW + quad*8], &ah0, &al0);
      afrag(&u.c.h1s[(rbase + 16 + l15)*HROW + quad*8], &ah1, &al1);
      f32x4 a00 = {0.f,0.f,0.f,0.f}, a01 = a00, a10 = a00, a11 = a00;
      a00 = __builtin_amdgcn_mfma_f32_16x16x32_bf16(ah0, bH0, a00, 0, 0, 0);
      a00 = __builtin_amdgcn_mfma_f32_16x16x32_bf16(ah0, bL0, a00, 0, 0, 0);
      a00 = __builtin_amdgcn_mfma_f32_16x16x32_bf16(al0, bH0, a00, 0, 0, 0);
      a01 = __builtin_amdgcn_mfma_f32_16x16x32_bf16(ah0, bH1, a01, 0, 0, 0);
      a01 = __builtin_amdgcn_mfma_f32_16x16x32_bf16(ah0, bL1, a01, 0, 0, 0);
      a01 = __builtin_amdgcn_mfma_f32_16x16x32_bf16(al0, bH1, a01, 0, 0, 0);
      a10 = __builtin_amdgcn_mfma_f32_16x16x32_bf16(ah1, bH0, a10, 0, 0, 0);
      a10 = __builtin_amdgcn_mfma_f32_16x16x32_bf16(ah1, bL0, a10, 0, 0, 0);
      a10 = __builtin_amdgcn_mfma_f32_16x16x32_bf16(al1, bH0, a10, 0, 0, 0);
      a11 = __builtin_amdgcn_mfma_f32_16x16x32_bf16(ah1, bH1, a11, 0, 0, 0);
      a11 = __builtin_amdgcn_mfma_f32_16x16x32_bf16(ah1, bL1, a11, 0, 0, 0);
      a11 = __builtin_amdgcn_mfma_f32_16x16x32_bf16(al1, bH1, a11, 0, 0, 0);
      float m0 = fmaxf(fmaxf(a00[0], a00[1]), fmaxf(a00[2], a00[3]));
      float m1 = fmaxf(fmaxf(a01[0], a01[1]), fmaxf(a01[2], a01[3]));
      if (quad == 0) { m0 = fmaxf(m0, a10[0]); m1 = fmaxf(m1, a11[0]); }
      m0 = fmaxf(m0, __shfl_xor(m0, 16)); m0 = fmaxf(m0, __shfl_xor(m0, 32));
      m1 = fmaxf(m1, __shfl_xor(m1, 16)); m1 = fmaxf(m1, __shfl_xor(m1, 32));
      if (quad == 0) {
        u.c.xs[n16][l15]      = fmaxf(m0 + bias0, 0.f);  // x1 = relu(max + b1b)
        u.c.xs[n16][16 + l15] = fmaxf(m1 + bias1, 0.f);
      }
    }
    __syncthreads();
    {
      int ns = tid >> 5;                            // 0..15
      float uu = 0.f;
      #pragma unroll
      for (int k4 = 0; k4 < 8; ++k4) {
        float4 x4 = *(const float4*)&u.c.xs[ns][4*k4];
        float4 w4 = *(const float4*)&u.c.wsaT[c32*HROW + 4*k4];
        uu += x4.x*w4.x + x4.y*w4.y + x4.z*w4.z + x4.w*w4.w;
      }
      g_u[(nbb + nloc0 + ns)*CH + c32] = uu;        // u = x1 @ w2a[0:32,:]
    }
    __syncthreads();
  }
}

// ---------------- conv2: 64 nodes/block (4 chunks x 16), cached fe, MFMA, reg block-max -
__global__ __launch_bounds__(512) void conv2_kernel() {
  __shared__ __align__(16) float fe[272][4];        //  4352 B
  __shared__ int jn[272];                           //  1088 B
  __shared__ __align__(16) float h1s[288*HROW];     // 41472 B
  __shared__ float xs[16][CH];                      //  2048 B
  const int tid = threadIdx.x;
  const int c = tid & 31;
  const int lane = tid & 63, wv = tid >> 6;
  const int quad = lane >> 4, l15 = lane & 15;
  const int node0 = blockIdx.x << 6;                // 64 nodes/block
  float w2aL_c[4];
  #pragma unroll
  for (int f = 0; f < 4; ++f) w2aL_c[f] = g_wts[OW2A + (CH + f)*CH + c];
  const float b2a_c = g_wts[OB2A + c];
  short8 bH0 = *(const short8*)&g_wfrag2[0][0][lane][0];
  short8 bL0 = *(const short8*)&g_wfrag2[0][1][lane][0];
  short8 bH1 = *(const short8*)&g_wfrag2[1][0][lane][0];
  short8 bL1 = *(const short8*)&g_wfrag2[1][1][lane][0];
  const float bias0 = g_wts[OB2B + l15];
  const float bias1 = g_wts[OB2B + 16 + l15];
  float bmx = 0.f;                                  // running block max (tid < 32)

  #pragma unroll 1
  for (int ck = 0; ck < 4; ++ck) {
    const int n0 = node0 + (ck << 4);
    if (tid < 272) {
      int ns = tid / 17, slot = tid - ns*17;
      int i = n0 + ns;
      jn[tid] = (slot < KK) ? g_nbr[i*KK + slot] : i;
      *(float4*)fe[tid] = g_fe4[(size_t)n0*SLOTS + tid];   // cached ppf (coalesced)
    }
    __syncthreads();
    #pragma unroll
    for (int it = 0; it < 17; ++it) {
      int idx = it*512 + tid;
      int e = idx >> 5;                             // 0..271
      float4 f4 = *(const float4*)fe[e];
      float uv = g_u[jn[e]*CH + c];                 // x_j @ w2a[0:32] precomputed
      float h = b2a_c + uv + f4.x*w2aL_c[0] + f4.y*w2aL_c[1] + f4.z*w2aL_c[2] + f4.w*w2aL_c[3];
      h1s[e*HROW + c] = fmaxf(h, 0.f);
    }
    __syncthreads();
    #pragma unroll
    for (int ni = 0; ni < 2; ++ni) {                // MFMA phase: 2 nodes/wave
      const int n16 = wv*2 + ni;
      const int rbase = n16*17;
      short8 ah0, al0, ah1, al1;
      afrag(&h1s[(rbase      + l15)*HROW + quad*8], &ah0, &al0);
      afrag(&h1s[(rbase + 16 + l15)*HROW + quad*8], &ah1, &al1);
      f32x4 a00 = {0.f,0.f,0.f,0.f}, a01 = a00, a10 = a00, a11 = a00;
      a00 = __builtin_amdgcn_mfma_f32_16x16x32_bf16(ah0, bH0, a00, 0, 0, 0);
      a00 = __builtin_amdgcn_mfma_f32_16x16x32_bf16(ah0, bL0, a00, 0, 0, 0);
      a00 = __builtin_amdgcn_mfma_f32_16x16x32_bf16(al0, bH0, a00, 0, 0, 0);
      a01 = __builtin_amdgcn_mfma_f32_16x16x32_bf16(ah0, bH1, a01, 0, 0, 0);
      a01 = __builtin_amdgcn_mfma_f32_16x16x32_bf16(ah0, bL1, a01, 0, 0, 0);
      a01 = __builtin_amdgcn_mfma_f32_16x16x32_bf16(al0, bH1, a01, 0, 0, 0);
      a10 = __builtin_amdgcn_mfma_f32_16x16x32_bf16(ah1, bH0, a10, 0, 0, 0);
      a10 = __builtin_amdgcn_mfma_f32_16x16x32_bf16(ah1, bL0, a10, 0, 0, 0);
      a10 = __builtin_amdgcn_mfma_f32_16x16x32_bf16(al1, bH0, a10, 0, 0, 0);
      a11 = __builtin_amdgcn_mfma_f32_16x16x32_bf16(ah1, bH1, a11, 0, 0, 0);
      a11 = __builtin_amdgcn_mfma_f32_16x16x32_bf16(ah1, bL1, a11, 0, 0, 0);
      a11 = __builtin_amdgcn_mfma_f32_16x16x32_bf16(al1, bH1, a11, 0, 0, 0);
      float m0 = fmaxf(fmaxf(a00[0], a00[1]), fmaxf(a00[2], a00[3]));
      float m1 = fmaxf(fmaxf(a01[0], a01[1]), fmaxf(a01[2], a01[3]));
      if (quad == 0) { m0 = fmaxf(m0, a10[0]); m1 = fmaxf(m1, a11[0]); }
      m0 = fmaxf(m0, __shfl_xor(m0, 16)); m0 = fmaxf(m0, __shfl_xor(m0, 32));
      m1 = fmaxf(m1, __shfl_xor(m1, 16)); m1 = fmaxf(m1, __shfl_xor(m1, 32));
      if (quad == 0) {
        xs[n16][l15]      = fmaxf(m0 + bias0, 0.f);      // x2 = relu(max + b2b)
        xs[n16][16 + l15] = fmaxf(m1 + bias1, 0.f);
      }
    }
    __syncthreads();
    if (tid < CH) {
      #pragma unroll
      for (int r = 0; r < 16; ++r) bmx = fmaxf(bmx, xs[r][c]);
    }
    __syncthreads();                                // xs reused next chunk
  }
  if (tid < CH) g_bmax[blockIdx.x*CH + c] = bmx;
}

// ---------------- head: two-stage max over g_bmax + 32->40 matmul (f32 out) -------------
__global__ __launch_bounds__(256) void head_kernel(float* __restrict__ out) {
  __shared__ float red[8][CH];
  __shared__ float gm[CH];
  const int g = blockIdx.x;
  const int c = threadIdx.x & 31, sub = threadIdx.x >> 5;
  const float* base = g_bmax + (size_t)(g*64 + sub*8)*CH;     // 64 conv2 blocks/graph
  float mx = 0.f;                                             // x2 >= 0 (relu)
  #pragma unroll
  for (int n = 0; n < 8; ++n) mx = fmaxf(mx, base[n*CH + c]);
  red[sub][c] = mx;
  __syncthreads();
  if (threadIdx.x < CH) {
    float m2 = red[0][c];
    #pragma unroll
    for (int r = 1; r < 8; ++r) m2 = fmaxf(m2, red[r][c]);
    gm[c] = m2;
  }
  __syncthreads();
  if (threadIdx.x < NCLS) {
    int co = threadIdx.x;
    float s = g_wts[OBC + co];
    #pragma unroll
    for (int f = 0; f < CH; ++f) s += gm[f] * g_wts[OWC + f*NCLS + co];
    out[g*NCLS + co] = s;                     // float32 out (reference dtype)
  }
}

extern "C" void kernel_launch(void* const* d_in, const int* in_sizes, int n_in,
                              void* d_out, int out_size, void* d_ws, size_t ws_size,
                              hipStream_t stream) {
  const void* pos = d_in[0];
  const void* nrm = d_in[1];
  // d_in[2] = batch (int32) -- unused, batches are uniform
  const void* w1a = d_in[3];
  const void* b1a = d_in[4];
  const void* w1b = d_in[5];
  const void* b1b = d_in[6];
  const void* w2a = d_in[7];
  const void* b2a = d_in[8];
  const void* w2b = d_in[9];
  const void* b2b = d_in[10];
  const void* wc  = d_in[11];
  const void* bc  = d_in[12];

  prep_kernel<<<MM/256, 256, 0, stream>>>(pos, nrm, w1a, b1a, w1b, b1b,
                                          w2a, b2a, w2b, b2b, wc, bc);
  knn_conv1_kernel<<<MM/64, 512, 0, stream>>>();
  conv2_kernel<<<MM/64, 512, 0, stream>>>();
  head_kernel<<<NB, 256, 0, stream>>>((float*)d_out);
}